// Round 4
// baseline (1164.350 us; speedup 1.0000x reference)
//
#include <hip/hip_runtime.h>
#include <hip/hip_bf16.h>
#include <math.h>

#define NB 32
#define NQ 2048
#define NK 512
#define NE 16
#define NH 32
#define NL 20
#define NHID 50
#define NO 41

// ws layout (floats): val [32][512][64] @ 0 (1,048,576); ktab [512][16] @ 1048576 (8,192)

__device__ __forceinline__ float fsigmoid(float x) {
  return __builtin_amdgcn_rcpf(1.0f + __expf(-x));
}
__device__ __forceinline__ float ftanh(float x) {
  return 1.0f - 2.0f * __builtin_amdgcn_rcpf(__expf(2.0f * x) + 1.0f);
}

__global__ __launch_bounds__(256) void prep_kernel(
    const float* __restrict__ refq, const float* __restrict__ Wk,
    const float* __restrict__ bk, float* __restrict__ ktab) {
  const int r = blockIdx.x * 256 + threadIdx.x;
  if (r >= NK) return;
  const float divs[8] = {1.0f, 0.74989421f, 0.56234133f, 0.42169650f,
                         0.31622777f, 0.23713737f, 0.17782794f, 0.13335214f};
  float pos = refq[r];
  float emb[NE];
#pragma unroll
  for (int m = 0; m < 8; ++m) {
    float a = 48.0f * pos * divs[m];
    emb[2 * m] = sinf(a);
    emb[2 * m + 1] = cosf(a);
  }
#pragma unroll
  for (int e = 0; e < NE; ++e) {
    float acc = bk[e];
#pragma unroll
    for (int i = 0; i < NE; ++i) acc += emb[i] * Wk[e * NE + i];
    ktab[r * NE + e] = acc;
  }
}

// One block (single wave) per chain; half-split dots + 4 shuffles per step.
// Single-wave LDS h: same-wave DS ops are in-order, no barrier in the loop.
__global__ __launch_bounds__(64) void gru_kernel(
    const float* __restrict__ z,
    const float* __restrict__ Wih_f, const float* __restrict__ bih_f,
    const float* __restrict__ Whh_f, const float* __restrict__ bhh_f,
    const float* __restrict__ Wih_b, const float* __restrict__ bih_b,
    const float* __restrict__ Whh_b, const float* __restrict__ bhh_b,
    float* __restrict__ val) {
  __shared__ __align__(16) float zs[NK * NL];  // 40 KB
  __shared__ __align__(16) float hbuf[NH];
  const int c = blockIdx.x;
  const int dir = c >> 5, b = c & 31;
  const int l = threadIdx.x;
  const int j = l & 31, half = l >> 5;
  const float* __restrict__ zb = z + (size_t)b * NK * NL;
  for (int i = l; i < NK * NL; i += 64) zs[i] = zb[i];

  const float* __restrict__ Wih = dir ? Wih_b : Wih_f;
  const float* __restrict__ bih = dir ? bih_b : bih_f;
  const float* __restrict__ Whh = dir ? Whh_b : Whh_f;
  const float* __restrict__ bhh = dir ? bhh_b : bhh_f;

  float ur[10], uz[10], un[10];
#pragma unroll
  for (int i = 0; i < 10; ++i) {
    ur[i] = Wih[j * NL + half * 10 + i];
    uz[i] = Wih[(j + 32) * NL + half * 10 + i];
    un[i] = Wih[(j + 64) * NL + half * 10 + i];
  }
  float wr[16], wz[16], wn[16];
#pragma unroll
  for (int i = 0; i < 16; ++i) {
    wr[i] = Whh[j * 32 + half * 16 + i];
    wz[i] = Whh[(j + 32) * 32 + half * 16 + i];
    wn[i] = Whh[(j + 64) * 32 + half * 16 + i];
  }
  const float Br = bih[j] + bhh[j];
  const float Bz = bih[j + 32] + bhh[j + 32];
  const float bin_ = bih[j + 64], bhn = bhh[j + 64];
  if (l < NH) hbuf[l] = 0.0f;
  __syncthreads();  // one-time: zs + hbuf visible

  float pir, piz, pin;
  auto inpart = [&](int s, float& xr, float& xz, float& xn) {
    const int tt = dir ? (NK - 1 - s) : s;
    const float* zr = &zs[tt * NL + half * 10];
    float ar = 0.f, az = 0.f, an = 0.f;
#pragma unroll
    for (int i = 0; i < 10; ++i) {
      const float zi = zr[i];
      ar += ur[i] * zi;
      az += uz[i] * zi;
      an += un[i] * zi;
    }
    xr = ar; xz = az; xn = an;
  };
  inpart(0, pir, piz, pin);

  for (int s = 0; s < NK; ++s) {
    const float4 h0 = *(const float4*)&hbuf[half * 16 + 0];
    const float4 h1 = *(const float4*)&hbuf[half * 16 + 4];
    const float4 h2 = *(const float4*)&hbuf[half * 16 + 8];
    const float4 h3 = *(const float4*)&hbuf[half * 16 + 12];
    const float hj = hbuf[j];
    float phr, phz, phn;
    {
      float ar, az, an;
      ar  = wr[0] * h0.x + wr[1] * h0.y + wr[2] * h0.z + wr[3] * h0.w;
      ar += wr[4] * h1.x + wr[5] * h1.y + wr[6] * h1.z + wr[7] * h1.w;
      ar += wr[8] * h2.x + wr[9] * h2.y + wr[10] * h2.z + wr[11] * h2.w;
      ar += wr[12] * h3.x + wr[13] * h3.y + wr[14] * h3.z + wr[15] * h3.w;
      az  = wz[0] * h0.x + wz[1] * h0.y + wz[2] * h0.z + wz[3] * h0.w;
      az += wz[4] * h1.x + wz[5] * h1.y + wz[6] * h1.z + wz[7] * h1.w;
      az += wz[8] * h2.x + wz[9] * h2.y + wz[10] * h2.z + wz[11] * h2.w;
      az += wz[12] * h3.x + wz[13] * h3.y + wz[14] * h3.z + wz[15] * h3.w;
      an  = wn[0] * h0.x + wn[1] * h0.y + wn[2] * h0.z + wn[3] * h0.w;
      an += wn[4] * h1.x + wn[5] * h1.y + wn[6] * h1.z + wn[7] * h1.w;
      an += wn[8] * h2.x + wn[9] * h2.y + wn[10] * h2.z + wn[11] * h2.w;
      an += wn[12] * h3.x + wn[13] * h3.y + wn[14] * h3.z + wn[15] * h3.w;
      phr = ar; phz = az; phn = an;
    }
    const float cr = pir + phr;
    const float cz = piz + phz;
    const float cni = pin;
    const float sr = cr + __shfl_xor(cr, 32);
    const float sz = cz + __shfl_xor(cz, 32);
    const float sni = cni + __shfl_xor(cni, 32);
    const float snh = phn + __shfl_xor(phn, 32);
    if (s + 1 < NK) inpart(s + 1, pir, piz, pin);  // fill shuffle/exp latency
    const float rg = fsigmoid(sr + Br);
    const float ug = fsigmoid(sz + Bz);
    const float ng = ftanh(sni + bin_ + rg * (snh + bhn));
    const float hnew = ng + ug * (hj - ng);
    hbuf[j] = hnew;  // both halves write same value; same-wave in-order
    if (half == 0) {
      const int tt = dir ? (NK - 1 - s) : s;
      val[((size_t)b * NK + tt) * 64 + dir * 32 + j] = hnew;
    }
  }
}

// In-place V' = V @ Wv^T + bv. One wave per row group; each wave owns its rows.
__global__ __launch_bounds__(256) void vproj_kernel(
    const float* __restrict__ Wv, const float* __restrict__ bv,
    float* __restrict__ val) {
  __shared__ float wv[64 * 65];
  __shared__ float bvs[64];
  __shared__ float rows[4][64];
  const int tid = threadIdx.x;
  for (int i = tid; i < 64 * 64; i += 256) wv[(i >> 6) * 65 + (i & 63)] = Wv[i];
  if (tid < 64) bvs[tid] = bv[tid];
  __syncthreads();
  const int grp = tid >> 6, d = tid & 63;
  const int row = blockIdx.x * 4 + grp;
  float* vr = val + (size_t)row * 64;
  rows[grp][d] = vr[d];  // wave-local stage; same-wave DS in-order
  float acc = bvs[d];
#pragma unroll
  for (int i = 0; i < 64; ++i) acc += rows[grp][i] * wv[d * 65 + i];
  vr[d] = acc;
}

// 4 threads per q-row (seg-interleaved k), 4 blocks/CU (LDS 34 KB).
__global__ __launch_bounds__(256, 4) void attn_kernel(
    const float* __restrict__ tsteps, const float* __restrict__ ktab,
    const float* __restrict__ val,
    const float* __restrict__ Wq, const float* __restrict__ bq,
    const float* __restrict__ W1, const float* __restrict__ b1,
    const float* __restrict__ W2, const float* __restrict__ b2,
    float* __restrict__ out) {
  __shared__ __align__(16) float kt[NK * NE];  // 32 KB
  __shared__ float wqs[NE * NE];
  __shared__ float bqs[NE], b1s[NHID];
  const int tid = threadIdx.x;
  for (int i = tid; i < NK * NE; i += 256) kt[i] = ktab[i];
  for (int i = tid; i < NE * NE; i += 256) wqs[i] = Wq[i];
  if (tid < NE) bqs[tid] = bq[tid];
  if (tid < NHID) b1s[tid] = b1[tid];
  __syncthreads();

  const int g = blockIdx.x * 256 + tid;
  const int row = g >> 2;        // b*2048 + qi
  const int seg = g & 3;
  const int b = row >> 11;
  const float pos = tsteps[row];
  const float divs[8] = {1.0f, 0.74989421f, 0.56234133f, 0.42169650f,
                         0.31622777f, 0.23713737f, 0.17782794f, 0.13335214f};
  float emb[NE];
#pragma unroll
  for (int m = 0; m < 8; ++m) {
    float a = 48.0f * pos * divs[m];
    emb[2 * m] = sinf(a);
    emb[2 * m + 1] = cosf(a);
  }
  float q[NE];
#pragma unroll
  for (int e = 0; e < NE; ++e) {
    float acc = bqs[e];
#pragma unroll
    for (int i = 0; i < NE; ++i) acc += emb[i] * wqs[e * NE + i];
    q[e] = acc;
  }
  const float* __restrict__ vb = val + (size_t)b * NK * 64;
  float att[64];
#pragma unroll
  for (int d = 0; d < 64; ++d) att[d] = 0.f;
  float lsum = 0.f;
#pragma unroll 2
  for (int kk = 0; kk < NK / 4; ++kk) {
    const int k = (kk << 2) | seg;  // wave reads 4 contiguous v rows (256 B)
    const float4* kr = (const float4*)&kt[k * NE];
    float s = 0.f;
#pragma unroll
    for (int e4 = 0; e4 < 4; ++e4) {
      float4 kkv = kr[e4];
      s += q[e4 * 4 + 0] * kkv.x + q[e4 * 4 + 1] * kkv.y +
           q[e4 * 4 + 2] * kkv.z + q[e4 * 4 + 3] * kkv.w;
    }
    const float p = __expf(s * 0.25f);  // scores O(1): no max-sub needed
    lsum += p;
    const float4* vr = (const float4*)(vb + (size_t)k * 64);
#pragma unroll
    for (int d4 = 0; d4 < 16; ++d4) {
      float4 vv = vr[d4];
      att[d4 * 4 + 0] += p * vv.x;
      att[d4 * 4 + 1] += p * vv.y;
      att[d4 * 4 + 2] += p * vv.z;
      att[d4 * 4 + 3] += p * vv.w;
    }
  }
  // combine the 4 k-segments (lanes differ only in bits 0..1)
  lsum += __shfl_xor(lsum, 1);
  lsum += __shfl_xor(lsum, 2);
#pragma unroll
  for (int d = 0; d < 64; ++d) {
    att[d] += __shfl_xor(att[d], 1);
    att[d] += __shfl_xor(att[d], 2);
  }
  const float inv = 1.0f / lsum;
#pragma unroll
  for (int d = 0; d < 64; ++d) att[d] *= inv;

  // interleaved MLP epilogue: one hidden unit at a time into 41 out accums
  float outv[NO];
#pragma unroll
  for (int oo = 0; oo < NO; ++oo) outv[oo] = b2[oo];
#pragma unroll 2
  for (int o = 0; o < NHID; ++o) {
    float acc = b1s[o];
    const float4* w4 = (const float4*)(W1 + o * 64);
#pragma unroll
    for (int i4 = 0; i4 < 16; ++i4) {
      float4 ww = w4[i4];
      acc += att[i4 * 4 + 0] * ww.x + att[i4 * 4 + 1] * ww.y +
             att[i4 * 4 + 2] * ww.z + att[i4 * 4 + 3] * ww.w;
    }
    const float hv = fmaxf(acc, 0.f);
#pragma unroll
    for (int oo = 0; oo < NO; ++oo) outv[oo] += hv * W2[oo * NHID + o];
  }
  if (seg == 0) {
    float* orow = out + (size_t)row * NO;
#pragma unroll
    for (int oo = 0; oo < NO; ++oo) orow[oo] = outv[oo];
  }
}

extern "C" void kernel_launch(void* const* d_in, const int* in_sizes, int n_in,
                              void* d_out, int out_size, void* d_ws, size_t ws_size,
                              hipStream_t stream) {
  const float* z = (const float*)d_in[0];
  const float* ts = (const float*)d_in[1];
  const float* refq = (const float*)d_in[2];
  const float* Wih_f = (const float*)d_in[3];
  const float* Whh_f = (const float*)d_in[4];
  const float* bih_f = (const float*)d_in[5];
  const float* bhh_f = (const float*)d_in[6];
  const float* Wih_b = (const float*)d_in[7];
  const float* Whh_b = (const float*)d_in[8];
  const float* bih_b = (const float*)d_in[9];
  const float* bhh_b = (const float*)d_in[10];
  const float* Wq = (const float*)d_in[11];
  const float* bq = (const float*)d_in[12];
  const float* Wk = (const float*)d_in[13];
  const float* bk = (const float*)d_in[14];
  const float* Wv = (const float*)d_in[15];
  const float* bv = (const float*)d_in[16];
  const float* W1 = (const float*)d_in[17];
  const float* b1 = (const float*)d_in[18];
  const float* W2 = (const float*)d_in[19];
  const float* b2 = (const float*)d_in[20];

  float* ws = (float*)d_ws;
  float* val = ws;             // 1,048,576 floats
  float* ktab = ws + 1048576;  // 8,192 floats
  float* out = (float*)d_out;

  prep_kernel<<<2, 256, 0, stream>>>(refq, Wk, bk, ktab);
  gru_kernel<<<64, 64, 0, stream>>>(z, Wih_f, bih_f, Whh_f, bhh_f,
                                    Wih_b, bih_b, Whh_b, bhh_b, val);
  vproj_kernel<<<4096, 256, 0, stream>>>(Wv, bv, val);
  attn_kernel<<<1024, 256, 0, stream>>>(ts, ktab, val, Wq, bq,
                                        W1, b1, W2, b2, out);
}

// Round 5
// 906.517 us; speedup vs baseline: 1.2844x; 1.2844x over previous
//
#include <hip/hip_runtime.h>
#include <hip/hip_bf16.h>
#include <math.h>

#define NB 32
#define NQ 2048
#define NK 512
#define NE 16
#define NH 32
#define NL 20
#define NHID 50
#define NO 41

// ws layout (floats):
// att  : [65536][64]  @ 0        (4,194,304)  raw P@val, pre-Wv
// val  : [32][512][64] @ 4194304 (1,048,576)
// ktab : [512][16]     @ 5242880 (8,192)
// total 5,251,072 floats = 21.0 MB

__device__ __forceinline__ float fsigmoid(float x) {
  return __builtin_amdgcn_rcpf(1.0f + __expf(-x));
}
__device__ __forceinline__ float ftanh(float x) {
  return 1.0f - 2.0f * __builtin_amdgcn_rcpf(__expf(2.0f * x) + 1.0f);
}

__global__ __launch_bounds__(256) void prep_kernel(
    const float* __restrict__ refq, const float* __restrict__ Wk,
    const float* __restrict__ bk, float* __restrict__ ktab) {
  const int r = blockIdx.x * 256 + threadIdx.x;
  if (r >= NK) return;
  const float divs[8] = {1.0f, 0.74989421f, 0.56234133f, 0.42169650f,
                         0.31622777f, 0.23713737f, 0.17782794f, 0.13335214f};
  float pos = refq[r];
  float emb[NE];
#pragma unroll
  for (int m = 0; m < 8; ++m) {
    float a = 48.0f * pos * divs[m];
    emb[2 * m] = sinf(a);
    emb[2 * m + 1] = cosf(a);
  }
#pragma unroll
  for (int e = 0; e < NE; ++e) {
    float acc = bk[e];
#pragma unroll
    for (int i = 0; i < NE; ++i) acc += emb[i] * Wk[e * NE + i];
    ktab[r * NE + e] = acc;
  }
}

// One block (single wave) per chain; half-split dots + 4 shuffles per step.
// Single-wave LDS h: same-wave DS ops are in-order, no barrier in the loop.
__global__ __launch_bounds__(64) void gru_kernel(
    const float* __restrict__ z,
    const float* __restrict__ Wih_f, const float* __restrict__ bih_f,
    const float* __restrict__ Whh_f, const float* __restrict__ bhh_f,
    const float* __restrict__ Wih_b, const float* __restrict__ bih_b,
    const float* __restrict__ Whh_b, const float* __restrict__ bhh_b,
    float* __restrict__ val) {
  __shared__ __align__(16) float zs[NK * NL];  // 40 KB
  __shared__ __align__(16) float hbuf[NH];
  const int c = blockIdx.x;
  const int dir = c >> 5, b = c & 31;
  const int l = threadIdx.x;
  const int j = l & 31, half = l >> 5;
  const float* __restrict__ zb = z + (size_t)b * NK * NL;
  for (int i = l; i < NK * NL; i += 64) zs[i] = zb[i];

  const float* __restrict__ Wih = dir ? Wih_b : Wih_f;
  const float* __restrict__ bih = dir ? bih_b : bih_f;
  const float* __restrict__ Whh = dir ? Whh_b : Whh_f;
  const float* __restrict__ bhh = dir ? bhh_b : bhh_f;

  float ur[10], uz[10], un[10];
#pragma unroll
  for (int i = 0; i < 10; ++i) {
    ur[i] = Wih[j * NL + half * 10 + i];
    uz[i] = Wih[(j + 32) * NL + half * 10 + i];
    un[i] = Wih[(j + 64) * NL + half * 10 + i];
  }
  float wr[16], wz[16], wn[16];
#pragma unroll
  for (int i = 0; i < 16; ++i) {
    wr[i] = Whh[j * 32 + half * 16 + i];
    wz[i] = Whh[(j + 32) * 32 + half * 16 + i];
    wn[i] = Whh[(j + 64) * 32 + half * 16 + i];
  }
  const float Br = bih[j] + bhh[j];
  const float Bz = bih[j + 32] + bhh[j + 32];
  const float bin_ = bih[j + 64], bhn = bhh[j + 64];
  if (l < NH) hbuf[l] = 0.0f;
  __syncthreads();  // one-time: zs + hbuf visible

  float pir, piz, pin;
  auto inpart = [&](int s, float& xr, float& xz, float& xn) {
    const int tt = dir ? (NK - 1 - s) : s;
    const float* zr = &zs[tt * NL + half * 10];
    float ar = 0.f, az = 0.f, an = 0.f;
#pragma unroll
    for (int i = 0; i < 10; ++i) {
      const float zi = zr[i];
      ar += ur[i] * zi;
      az += uz[i] * zi;
      an += un[i] * zi;
    }
    xr = ar; xz = az; xn = an;
  };
  inpart(0, pir, piz, pin);

  for (int s = 0; s < NK; ++s) {
    const float4 h0 = *(const float4*)&hbuf[half * 16 + 0];
    const float4 h1 = *(const float4*)&hbuf[half * 16 + 4];
    const float4 h2 = *(const float4*)&hbuf[half * 16 + 8];
    const float4 h3 = *(const float4*)&hbuf[half * 16 + 12];
    const float hj = hbuf[j];
    float phr, phz, phn;
    {
      float ar, az, an;
      ar  = wr[0] * h0.x + wr[1] * h0.y + wr[2] * h0.z + wr[3] * h0.w;
      ar += wr[4] * h1.x + wr[5] * h1.y + wr[6] * h1.z + wr[7] * h1.w;
      ar += wr[8] * h2.x + wr[9] * h2.y + wr[10] * h2.z + wr[11] * h2.w;
      ar += wr[12] * h3.x + wr[13] * h3.y + wr[14] * h3.z + wr[15] * h3.w;
      az  = wz[0] * h0.x + wz[1] * h0.y + wz[2] * h0.z + wz[3] * h0.w;
      az += wz[4] * h1.x + wz[5] * h1.y + wz[6] * h1.z + wz[7] * h1.w;
      az += wz[8] * h2.x + wz[9] * h2.y + wz[10] * h2.z + wz[11] * h2.w;
      az += wz[12] * h3.x + wz[13] * h3.y + wz[14] * h3.z + wz[15] * h3.w;
      an  = wn[0] * h0.x + wn[1] * h0.y + wn[2] * h0.z + wn[3] * h0.w;
      an += wn[4] * h1.x + wn[5] * h1.y + wn[6] * h1.z + wn[7] * h1.w;
      an += wn[8] * h2.x + wn[9] * h2.y + wn[10] * h2.z + wn[11] * h2.w;
      an += wn[12] * h3.x + wn[13] * h3.y + wn[14] * h3.z + wn[15] * h3.w;
      phr = ar; phz = az; phn = an;
    }
    const float cr = pir + phr;
    const float cz = piz + phz;
    const float cni = pin;
    const float sr = cr + __shfl_xor(cr, 32);
    const float sz = cz + __shfl_xor(cz, 32);
    const float sni = cni + __shfl_xor(cni, 32);
    const float snh = phn + __shfl_xor(phn, 32);
    if (s + 1 < NK) inpart(s + 1, pir, piz, pin);  // fill shuffle/exp latency
    const float rg = fsigmoid(sr + Br);
    const float ug = fsigmoid(sz + Bz);
    const float ng = ftanh(sni + bin_ + rg * (snh + bhn));
    const float hnew = ng + ug * (hj - ng);
    hbuf[j] = hnew;  // both halves write same value; same-wave in-order
    if (half == 0) {
      const int tt = dir ? (NK - 1 - s) : s;
      val[((size_t)b * NK + tt) * 64 + dir * 32 + j] = hnew;
    }
  }
}

// 1 thread per q-row; LDS = kt only (33 KB -> 4 blocks/CU, 16 waves/CU).
// v rows are wave-uniform broadcast loads from L2-resident val. Writes raw
// normalized P@val to ws; Wv/MLP applied by mlp_kernel.
__global__ __launch_bounds__(256, 4) void attn_core_kernel(
    const float* __restrict__ tsteps, const float* __restrict__ ktab,
    const float* __restrict__ val,
    const float* __restrict__ Wq, const float* __restrict__ bq,
    float* __restrict__ att) {
  __shared__ __align__(16) float kt[NK * NE];  // 32 KB
  __shared__ float wqs[NE * NE];
  __shared__ float bqs[NE];
  const int tid = threadIdx.x;
  for (int i = tid; i < NK * NE; i += 256) kt[i] = ktab[i];
  for (int i = tid; i < NE * NE; i += 256) wqs[i] = Wq[i];
  if (tid < NE) bqs[tid] = bq[tid];
  __syncthreads();

  const int row = blockIdx.x * 256 + tid;  // b*2048 + qi
  const int b = row >> 11;
  const float pos = tsteps[row];
  const float divs[8] = {1.0f, 0.74989421f, 0.56234133f, 0.42169650f,
                         0.31622777f, 0.23713737f, 0.17782794f, 0.13335214f};
  float emb[NE];
#pragma unroll
  for (int m = 0; m < 8; ++m) {
    float a = 48.0f * pos * divs[m];
    emb[2 * m] = sinf(a);
    emb[2 * m + 1] = cosf(a);
  }
  float q[NE];
#pragma unroll
  for (int e = 0; e < NE; ++e) {
    float acc = bqs[e];
#pragma unroll
    for (int i = 0; i < NE; ++i) acc += emb[i] * wqs[e * NE + i];
    q[e] = acc;
  }
  const float* __restrict__ vb = val + (size_t)b * NK * 64;
  float acc[64];
#pragma unroll
  for (int d = 0; d < 64; ++d) acc[d] = 0.f;
  float lsum = 0.f;
  // scores O(1) (0.1-scale weights): exp without max-sub safe in fp32
#pragma unroll 2
  for (int k = 0; k < NK; ++k) {
    const float4* kr = (const float4*)&kt[k * NE];  // wave-uniform broadcast
    float s = 0.f;
#pragma unroll
    for (int e4 = 0; e4 < 4; ++e4) {
      float4 kk = kr[e4];
      s += q[e4 * 4 + 0] * kk.x + q[e4 * 4 + 1] * kk.y +
           q[e4 * 4 + 2] * kk.z + q[e4 * 4 + 3] * kk.w;
    }
    const float p = __expf(s * 0.25f);
    lsum += p;
    const float4* vr = (const float4*)(vb + (size_t)k * 64);  // wave-uniform
#pragma unroll
    for (int d4 = 0; d4 < 16; ++d4) {
      float4 vv = vr[d4];
      acc[d4 * 4 + 0] += p * vv.x;
      acc[d4 * 4 + 1] += p * vv.y;
      acc[d4 * 4 + 2] += p * vv.z;
      acc[d4 * 4 + 3] += p * vv.w;
    }
  }
  const float inv = 1.0f / lsum;
  float4* ao = (float4*)(att + (size_t)row * 64);
#pragma unroll
  for (int d4 = 0; d4 < 16; ++d4) {
    float4 o;
    o.x = acc[d4 * 4 + 0] * inv;
    o.y = acc[d4 * 4 + 1] * inv;
    o.z = acc[d4 * 4 + 2] * inv;
    o.w = acc[d4 * 4 + 3] * inv;
    ao[d4] = o;
  }
}

// Per-row MLP with folded v-projection: softmax rows sum to 1 =>
// P@(val*Wv^T+bv) == (P@val)*Wv^T+bv. All weights staged in LDS (37.5 KB).
__global__ __launch_bounds__(256, 4) void mlp_kernel(
    const float* __restrict__ att,
    const float* __restrict__ Wv, const float* __restrict__ bv,
    const float* __restrict__ W1, const float* __restrict__ b1,
    const float* __restrict__ W2, const float* __restrict__ b2,
    float* __restrict__ out) {
  __shared__ __align__(16) float wvs[64 * 64];     // 16 KB
  __shared__ __align__(16) float w1s[NHID * 64];   // 12.8 KB
  __shared__ __align__(16) float w2s[NO * NHID];   // 8.2 KB
  __shared__ float bvs[64], b1s[NHID], b2s[NO];
  const int tid = threadIdx.x;
  for (int i = tid; i < 64 * 64; i += 256) wvs[i] = Wv[i];
  for (int i = tid; i < NHID * 64; i += 256) w1s[i] = W1[i];
  for (int i = tid; i < NO * NHID; i += 256) w2s[i] = W2[i];
  if (tid < 64) bvs[tid] = bv[tid];
  if (tid < NHID) b1s[tid] = b1[tid];
  if (tid < NO) b2s[tid] = b2[tid];
  __syncthreads();

  const int row = blockIdx.x * 256 + tid;
  float ar[64];
  const float4* a4 = (const float4*)(att + (size_t)row * 64);
#pragma unroll
  for (int d4 = 0; d4 < 16; ++d4) {
    float4 v = a4[d4];
    ar[d4 * 4 + 0] = v.x;
    ar[d4 * 4 + 1] = v.y;
    ar[d4 * 4 + 2] = v.z;
    ar[d4 * 4 + 3] = v.w;
  }
  float av[64];
#pragma unroll 4
  for (int d = 0; d < 64; ++d) {
    float acc = bvs[d];
    const float4* w4 = (const float4*)&wvs[d * 64];  // wave-uniform broadcast
#pragma unroll
    for (int i4 = 0; i4 < 16; ++i4) {
      float4 ww = w4[i4];
      acc += ar[i4 * 4 + 0] * ww.x + ar[i4 * 4 + 1] * ww.y +
             ar[i4 * 4 + 2] * ww.z + ar[i4 * 4 + 3] * ww.w;
    }
    av[d] = acc;
  }
  float h[NHID];
#pragma unroll 2
  for (int o = 0; o < NHID; ++o) {
    float acc = b1s[o];
    const float4* w4 = (const float4*)&w1s[o * 64];
#pragma unroll
    for (int i4 = 0; i4 < 16; ++i4) {
      float4 ww = w4[i4];
      acc += av[i4 * 4 + 0] * ww.x + av[i4 * 4 + 1] * ww.y +
             av[i4 * 4 + 2] * ww.z + av[i4 * 4 + 3] * ww.w;
    }
    h[o] = fmaxf(acc, 0.f);
  }
  float* orow = out + (size_t)row * NO;
#pragma unroll 2
  for (int oo = 0; oo < NO; ++oo) {
    float acc = b2s[oo];
#pragma unroll
    for (int o = 0; o < NHID; ++o) acc += h[o] * w2s[oo * NHID + o];
    orow[oo] = acc;
  }
}

extern "C" void kernel_launch(void* const* d_in, const int* in_sizes, int n_in,
                              void* d_out, int out_size, void* d_ws, size_t ws_size,
                              hipStream_t stream) {
  const float* z = (const float*)d_in[0];
  const float* ts = (const float*)d_in[1];
  const float* refq = (const float*)d_in[2];
  const float* Wih_f = (const float*)d_in[3];
  const float* Whh_f = (const float*)d_in[4];
  const float* bih_f = (const float*)d_in[5];
  const float* bhh_f = (const float*)d_in[6];
  const float* Wih_b = (const float*)d_in[7];
  const float* Whh_b = (const float*)d_in[8];
  const float* bih_b = (const float*)d_in[9];
  const float* bhh_b = (const float*)d_in[10];
  const float* Wq = (const float*)d_in[11];
  const float* bq = (const float*)d_in[12];
  const float* Wk = (const float*)d_in[13];
  const float* bk = (const float*)d_in[14];
  const float* Wv = (const float*)d_in[15];
  const float* bv = (const float*)d_in[16];
  const float* W1 = (const float*)d_in[17];
  const float* b1 = (const float*)d_in[18];
  const float* W2 = (const float*)d_in[19];
  const float* b2 = (const float*)d_in[20];

  float* ws = (float*)d_ws;
  float* att = ws;              // 4,194,304 floats
  float* val = ws + 4194304;    // 1,048,576 floats
  float* ktab = ws + 5242880;   // 8,192 floats
  float* out = (float*)d_out;

  prep_kernel<<<2, 256, 0, stream>>>(refq, Wk, bk, ktab);
  gru_kernel<<<64, 64, 0, stream>>>(z, Wih_f, bih_f, Whh_f, bhh_f,
                                    Wih_b, bih_b, Whh_b, bhh_b, val);
  attn_core_kernel<<<256, 256, 0, stream>>>(ts, ktab, val, Wq, bq, att);
  mlp_kernel<<<256, 256, 0, stream>>>(att, Wv, bv, W1, b1, W2, b2, out);
}

// Round 6
// 722.840 us; speedup vs baseline: 1.6108x; 1.2541x over previous
//
#include <hip/hip_runtime.h>
#include <hip/hip_bf16.h>
#include <math.h>

#define NB 32
#define NQ 2048
#define NK 512
#define NE 16
#define NH 32
#define NL 20
#define NHID 50
#define NO 41

// ws layout (floats):
// att  : [65536][64]   @ 0        (4,194,304)  normalized P@val (pre-Wv)
// val  : [32][512][64] @ 4194304  (1,048,576)
// ktab : [512][16]     @ 5242880  (8,192)
// w1p  : [50][64]      @ 5251072  (3,200)      W1 @ Wv
// b1p  : [50]          @ 5254272  (50)         b1 + W1 @ bv
// total ~21.0 MB (round-5-proven size)

__device__ __forceinline__ float fsigmoid(float x) {
  return __builtin_amdgcn_rcpf(1.0f + __expf(-x));
}
__device__ __forceinline__ float ftanh(float x) {
  return 1.0f - 2.0f * __builtin_amdgcn_rcpf(__expf(2.0f * x) + 1.0f);
}

// blocks 0-1: k-table. block 2: fold Wv into W1 (softmax rows sum to 1 =>
// P@(val@Wv^T+bv) == (P@val)@Wv^T+bv; then W1@(ar@Wv^T+bv) = (W1@Wv)@ar + (b1+W1@bv)).
__global__ __launch_bounds__(256) void prep_kernel(
    const float* __restrict__ refq, const float* __restrict__ Wk,
    const float* __restrict__ bk,
    const float* __restrict__ Wv, const float* __restrict__ bv,
    const float* __restrict__ W1, const float* __restrict__ b1,
    float* __restrict__ ktab, float* __restrict__ w1p,
    float* __restrict__ b1p) {
  const int tid = threadIdx.x;
  if (blockIdx.x < 2) {
    const int r = blockIdx.x * 256 + tid;
    const float divs[8] = {1.0f, 0.74989421f, 0.56234133f, 0.42169650f,
                           0.31622777f, 0.23713737f, 0.17782794f, 0.13335214f};
    float pos = refq[r];
    float emb[NE];
#pragma unroll
    for (int m = 0; m < 8; ++m) {
      float a = 48.0f * pos * divs[m];
      emb[2 * m] = sinf(a);
      emb[2 * m + 1] = cosf(a);
    }
#pragma unroll
    for (int e = 0; e < NE; ++e) {
      float acc = bk[e];
#pragma unroll
      for (int i = 0; i < NE; ++i) acc += emb[i] * Wk[e * NE + i];
      ktab[r * NE + e] = acc;
    }
  } else {
    for (int e = tid; e < NHID * 64; e += 256) {
      const int o = e >> 6, i = e & 63;
      float acc = 0.f;
#pragma unroll 4
      for (int d = 0; d < 64; ++d) acc += W1[o * 64 + d] * Wv[d * 64 + i];
      w1p[e] = acc;
    }
    if (tid < NHID) {
      float acc = b1[tid];
#pragma unroll 4
      for (int d = 0; d < 64; ++d) acc += W1[tid * 64 + d] * bv[d];
      b1p[tid] = acc;
    }
  }
}

// One wave per chain. h lives in REGISTERS (lane l holds h of unit l&31);
// per-step gather of the 16 partner h-values via __shfl (ds_bpermute) —
// no LDS write->read on the recurrence critical path.
__global__ __launch_bounds__(64) void gru_kernel(
    const float* __restrict__ z,
    const float* __restrict__ Wih_f, const float* __restrict__ bih_f,
    const float* __restrict__ Whh_f, const float* __restrict__ bhh_f,
    const float* __restrict__ Wih_b, const float* __restrict__ bih_b,
    const float* __restrict__ Whh_b, const float* __restrict__ bhh_b,
    float* __restrict__ val) {
  __shared__ __align__(16) float zs[NK * NL];  // 40 KB
  const int c = blockIdx.x;
  const int dir = c >> 5, b = c & 31;
  const int l = threadIdx.x;
  const int j = l & 31, half = l >> 5;
  const int hbase = half * 16;  // lanes 0-31 gather units 0-15; 32-63 -> 16-31
  const float* __restrict__ zb = z + (size_t)b * NK * NL;
  for (int i = l; i < NK * NL; i += 64) zs[i] = zb[i];

  const float* __restrict__ Wih = dir ? Wih_b : Wih_f;
  const float* __restrict__ bih = dir ? bih_b : bih_f;
  const float* __restrict__ Whh = dir ? Whh_b : Whh_f;
  const float* __restrict__ bhh = dir ? bhh_b : bhh_f;

  float ur[10], uz[10], un[10];
#pragma unroll
  for (int i = 0; i < 10; ++i) {
    ur[i] = Wih[j * NL + half * 10 + i];
    uz[i] = Wih[(j + 32) * NL + half * 10 + i];
    un[i] = Wih[(j + 64) * NL + half * 10 + i];
  }
  float wr[16], wz[16], wn[16];
#pragma unroll
  for (int i = 0; i < 16; ++i) {
    wr[i] = Whh[j * 32 + hbase + i];
    wz[i] = Whh[(j + 32) * 32 + hbase + i];
    wn[i] = Whh[(j + 64) * 32 + hbase + i];
  }
  const float Br = bih[j] + bhh[j];
  const float Bz = bih[j + 32] + bhh[j + 32];
  const float bin_ = bih[j + 64], bhn = bhh[j + 64];
  float h = 0.f;  // unit j, replicated in both wave halves
  __syncthreads();  // zs visible

  float pir, piz, pin;
  auto inpart = [&](int s, float& xr, float& xz, float& xn) {
    const int tt = dir ? (NK - 1 - s) : s;
    const float* zr = &zs[tt * NL + half * 10];
    float ar = 0.f, az = 0.f, an = 0.f;
#pragma unroll
    for (int i = 0; i < 10; ++i) {
      const float zi = zr[i];
      ar += ur[i] * zi;
      az += uz[i] * zi;
      an += un[i] * zi;
    }
    xr = ar; xz = az; xn = an;
  };
  inpart(0, pir, piz, pin);

  for (int s = 0; s < NK; ++s) {
    float hv[16];
#pragma unroll
    for (int t = 0; t < 16; ++t) hv[t] = __shfl(h, hbase + t);
    float pr0 = 0.f, pr1 = 0.f, pz0 = 0.f, pz1 = 0.f, pn0 = 0.f, pn1 = 0.f;
#pragma unroll
    for (int t = 0; t < 8; ++t) {
      pr0 += wr[t] * hv[t];
      pz0 += wz[t] * hv[t];
      pn0 += wn[t] * hv[t];
      pr1 += wr[8 + t] * hv[8 + t];
      pz1 += wz[8 + t] * hv[8 + t];
      pn1 += wn[8 + t] * hv[8 + t];
    }
    const float cr = pir + pr0 + pr1;
    const float cz = piz + pz0 + pz1;
    const float phn = pn0 + pn1;
    const float cni = pin;
    const float sr = cr + __shfl_xor(cr, 32);
    const float sz = cz + __shfl_xor(cz, 32);
    const float sni = cni + __shfl_xor(cni, 32);
    const float snh = phn + __shfl_xor(phn, 32);
    if (s + 1 < NK) inpart(s + 1, pir, piz, pin);  // independent: fills stalls
    const float rg = fsigmoid(sr + Br);
    const float ug = fsigmoid(sz + Bz);
    const float ng = ftanh(sni + bin_ + rg * (snh + bhn));
    h = ng + ug * (h - ng);
    if (half == 0) {
      const int tt = dir ? (NK - 1 - s) : s;
      val[((size_t)b * NK + tt) * 64 + dir * 32 + j] = h;
    }
  }
}

// d-split: 4 threads per q-row, each owns 16 of the 64 output dims.
// Score computed per thread (redundant x4, 16 FMA) -> no combine shuffles,
// each thread has the full lsum. acc[16] stays in VGPRs (no minwaves cap).
__global__ __launch_bounds__(256) void attn_core_kernel(
    const float* __restrict__ tsteps, const float* __restrict__ ktab,
    const float* __restrict__ val,
    const float* __restrict__ Wq, const float* __restrict__ bq,
    float* __restrict__ att) {
  __shared__ __align__(16) float kt[NK * NE];  // 32 KB
  __shared__ float wqs[NE * NE];
  __shared__ float bqs[NE];
  const int tid = threadIdx.x;
  for (int i = tid; i < NK * NE; i += 256) kt[i] = ktab[i];
  for (int i = tid; i < NE * NE; i += 256) wqs[i] = Wq[i];
  if (tid < NE) bqs[tid] = bq[tid];
  __syncthreads();

  const int g = blockIdx.x * 256 + tid;
  const int row = g >> 2;      // b*2048 + qi
  const int dq = g & 3;        // d-quarter
  const int b = row >> 11;
  const float pos = tsteps[row];
  const float divs[8] = {1.0f, 0.74989421f, 0.56234133f, 0.42169650f,
                         0.31622777f, 0.23713737f, 0.17782794f, 0.13335214f};
  float emb[NE];
#pragma unroll
  for (int m = 0; m < 8; ++m) {
    float a = 48.0f * pos * divs[m];
    emb[2 * m] = sinf(a);
    emb[2 * m + 1] = cosf(a);
  }
  float q[NE];
#pragma unroll
  for (int e = 0; e < NE; ++e) {
    float acc = bqs[e];
#pragma unroll
    for (int i = 0; i < NE; ++i) acc += emb[i] * wqs[e * NE + i];
    q[e] = acc;
  }
  const float* __restrict__ vb = val + (size_t)b * NK * 64 + dq * 16;
  float acc[16];
#pragma unroll
  for (int d = 0; d < 16; ++d) acc[d] = 0.f;
  float lsum = 0.f;
  // scores O(1) (0.1-scale weights): exp without max-sub safe in fp32
#pragma unroll 2
  for (int k = 0; k < NK; ++k) {
    const float4* kr = (const float4*)&kt[k * NE];  // uniform across wave
    float s = 0.f;
#pragma unroll
    for (int e4 = 0; e4 < 4; ++e4) {
      float4 kk = kr[e4];
      s += q[e4 * 4 + 0] * kk.x + q[e4 * 4 + 1] * kk.y +
           q[e4 * 4 + 2] * kk.z + q[e4 * 4 + 3] * kk.w;
    }
    const float p = __expf(s * 0.25f);
    lsum += p;
    const float4* vr = (const float4*)(vb + (size_t)k * 64);
    const float4 v0 = vr[0], v1 = vr[1], v2 = vr[2], v3 = vr[3];
    acc[0] += p * v0.x;  acc[1] += p * v0.y;
    acc[2] += p * v0.z;  acc[3] += p * v0.w;
    acc[4] += p * v1.x;  acc[5] += p * v1.y;
    acc[6] += p * v1.z;  acc[7] += p * v1.w;
    acc[8] += p * v2.x;  acc[9] += p * v2.y;
    acc[10] += p * v2.z; acc[11] += p * v2.w;
    acc[12] += p * v3.x; acc[13] += p * v3.y;
    acc[14] += p * v3.z; acc[15] += p * v3.w;
  }
  const float inv = 1.0f / lsum;
  float4* ao = (float4*)(att + (size_t)row * 64 + dq * 16);
#pragma unroll
  for (int d4 = 0; d4 < 4; ++d4) {
    float4 o;
    o.x = acc[d4 * 4 + 0] * inv;
    o.y = acc[d4 * 4 + 1] * inv;
    o.z = acc[d4 * 4 + 2] * inv;
    o.w = acc[d4 * 4 + 3] * inv;
    ao[d4] = o;
  }
}

// Per-row MLP on folded weights: out = W2 @ relu(W1' @ ar + b1') + b2.
// ~110 live VGPRs, no minwaves cap -> no spill.
__global__ __launch_bounds__(256) void mlp_kernel(
    const float* __restrict__ att,
    const float* __restrict__ w1p, const float* __restrict__ b1p,
    const float* __restrict__ W2, const float* __restrict__ b2,
    float* __restrict__ out) {
  __shared__ __align__(16) float w1s[NHID * 64];   // 12.8 KB
  __shared__ __align__(16) float w2s[NO * NHID];   // 8.2 KB
  __shared__ float b1s[NHID], b2s[NO];
  const int tid = threadIdx.x;
  for (int i = tid; i < NHID * 64; i += 256) w1s[i] = w1p[i];
  for (int i = tid; i < NO * NHID; i += 256) w2s[i] = W2[i];
  if (tid < NHID) b1s[tid] = b1p[tid];
  if (tid < NO) b2s[tid] = b2[tid];
  __syncthreads();

  const int row = blockIdx.x * 256 + tid;
  float ar[64];
  const float4* a4 = (const float4*)(att + (size_t)row * 64);
#pragma unroll
  for (int d4 = 0; d4 < 16; ++d4) {
    float4 v = a4[d4];
    ar[d4 * 4 + 0] = v.x;
    ar[d4 * 4 + 1] = v.y;
    ar[d4 * 4 + 2] = v.z;
    ar[d4 * 4 + 3] = v.w;
  }
  float outv[NO];
#pragma unroll
  for (int oo = 0; oo < NO; ++oo) outv[oo] = b2s[oo];
#pragma unroll 2
  for (int o = 0; o < NHID; ++o) {
    float acc = b1s[o];
    const float4* w4 = (const float4*)&w1s[o * 64];  // uniform broadcast
#pragma unroll
    for (int i4 = 0; i4 < 16; ++i4) {
      float4 ww = w4[i4];
      acc += ar[i4 * 4 + 0] * ww.x + ar[i4 * 4 + 1] * ww.y +
             ar[i4 * 4 + 2] * ww.z + ar[i4 * 4 + 3] * ww.w;
    }
    const float hv = fmaxf(acc, 0.f);
#pragma unroll
    for (int oo = 0; oo < NO; ++oo) outv[oo] += hv * w2s[oo * NHID + o];
  }
  float* orow = out + (size_t)row * NO;
#pragma unroll
  for (int oo = 0; oo < NO; ++oo) orow[oo] = outv[oo];
}

extern "C" void kernel_launch(void* const* d_in, const int* in_sizes, int n_in,
                              void* d_out, int out_size, void* d_ws, size_t ws_size,
                              hipStream_t stream) {
  const float* z = (const float*)d_in[0];
  const float* ts = (const float*)d_in[1];
  const float* refq = (const float*)d_in[2];
  const float* Wih_f = (const float*)d_in[3];
  const float* Whh_f = (const float*)d_in[4];
  const float* bih_f = (const float*)d_in[5];
  const float* bhh_f = (const float*)d_in[6];
  const float* Wih_b = (const float*)d_in[7];
  const float* Whh_b = (const float*)d_in[8];
  const float* bih_b = (const float*)d_in[9];
  const float* bhh_b = (const float*)d_in[10];
  const float* Wq = (const float*)d_in[11];
  const float* bq = (const float*)d_in[12];
  const float* Wk = (const float*)d_in[13];
  const float* bk = (const float*)d_in[14];
  const float* Wv = (const float*)d_in[15];
  const float* bv = (const float*)d_in[16];
  const float* W1 = (const float*)d_in[17];
  const float* b1 = (const float*)d_in[18];
  const float* W2 = (const float*)d_in[19];
  const float* b2 = (const float*)d_in[20];

  float* ws = (float*)d_ws;
  float* att = ws;              // 4,194,304
  float* val = ws + 4194304;    // 1,048,576
  float* ktab = ws + 5242880;   // 8,192
  float* w1p = ws + 5251072;    // 3,200
  float* b1p = ws + 5254272;    // 50
  float* out = (float*)d_out;

  prep_kernel<<<3, 256, 0, stream>>>(refq, Wk, bk, Wv, bv, W1, b1,
                                     ktab, w1p, b1p);
  gru_kernel<<<64, 64, 0, stream>>>(z, Wih_f, bih_f, Whh_f, bhh_f,
                                    Wih_b, bih_b, Whh_b, bhh_b, val);
  attn_core_kernel<<<1024, 256, 0, stream>>>(ts, ktab, val, Wq, bq, att);
  mlp_kernel<<<256, 256, 0, stream>>>(att, w1p, b1p, W2, b2, out);
}